// Round 1
// baseline (1525.846 us; speedup 1.0000x reference)
//
#include <hip/hip_runtime.h>

// DAHHConv: out = Dn^-1 H De^-1 H^T (x @ theta)
// N=20000 nodes, E=10000 edges, in=128, out=64. H is DENSE f32 [N,E] = 800MB.
// Strategy: two HBM-bound streaming passes over H with bf16 MFMA 16x16x32.
//   pass2: edgeT[c][e] = sum_n xwT[c][n]*H[n][e]  (A=xwT bf16 L2-resident, B=H natural layout)
//   pass3: out[n][c]  = sum_e H[n][e]*edgeT[c][e] (A=H natural layout, B=edgeT L2-resident)
// Degrees de/dn computed as f32 side-sums in the same passes. K-split + f32 atomics
// for occupancy. No LDS / no barriers in the main kernels.

#define N_ROWS 20000
#define E_COLS 10000
#define E_PAD  10016   // pad edge buffers to mult of 32, zero-filled tail
#define OUT_CH 64

typedef __attribute__((ext_vector_type(4))) float f32x4;
typedef __attribute__((ext_vector_type(8))) short s16x8;

__device__ __forceinline__ unsigned short f2bf(float f) {
  // round-to-nearest-even f32 -> bf16 (inputs are finite; no NaN handling needed)
  unsigned int u = __float_as_uint(f);
  u += 0x7FFFu + ((u >> 16) & 1u);
  return (unsigned short)(u >> 16);
}

// ---------------- kernel 1: xwT[c][n] = (x @ theta)^T, stored bf16 ----------------
__global__ __launch_bounds__(256) void k1_xwt(const float* __restrict__ x,
                                              const float* __restrict__ theta,
                                              unsigned short* __restrict__ xwT) {
  __shared__ float xt[64][129];  // +1 pad: conflict-free column reads
  const int n0 = blockIdx.x * 64;
  const int t  = threadIdx.x;
  // stage x tile [64][128] coalesced (float4), scalar LDS writes
  #pragma unroll
  for (int i = 0; i < 8; ++i) {
    int f  = t + 256 * i;            // float4 index 0..2047
    int r  = f >> 5;
    int c4 = (f & 31) * 4;
    float4 v = make_float4(0.f, 0.f, 0.f, 0.f);
    if (n0 + r < N_ROWS) v = *(const float4*)&x[(long)(n0 + r) * 128 + c4];
    xt[r][c4] = v.x; xt[r][c4 + 1] = v.y; xt[r][c4 + 2] = v.z; xt[r][c4 + 3] = v.w;
  }
  __syncthreads();
  const int nl = t & 63;            // lane == node row -> coalesced bf16 stores
  const int cg = t >> 6;            // wave-uniform -> theta reads become s_loads
  const int n  = n0 + nl;
  float acc[16];
  #pragma unroll
  for (int i = 0; i < 16; ++i) acc[i] = 0.f;
  #pragma unroll 4
  for (int k = 0; k < 128; ++k) {
    float xv = xt[nl][k];
    const float* th = theta + k * 64 + cg * 16;
    #pragma unroll
    for (int i = 0; i < 16; ++i) acc[i] += xv * th[i];
  }
  if (n < N_ROWS) {
    #pragma unroll
    for (int i = 0; i < 16; ++i)
      xwT[(long)(cg * 16 + i) * N_ROWS + n] = f2bf(acc[i]);  // 128B coalesced per store instr
  }
}

// ---------------- kernel 2: eacc[c][e] += sum_n xwT[c][n]*H[n][e]; de[e] += colsum ----
// grid: 625 e-tiles x 5 K-chunks = 3125 blocks of 1 wave. 20000 = 625*32 ksteps, 125/chunk.
__global__ __launch_bounds__(64) void k2_edge(const float* __restrict__ H,
                                              const unsigned short* __restrict__ xwT,
                                              float* __restrict__ eacc,
                                              float* __restrict__ de) {
  const int b  = blockIdx.x;
  const int et = b % 625, s = b / 625;
  const int e0 = et * 16;
  const int l  = threadIdx.x;
  const int q  = l >> 4, eL = l & 15;
  f32x4 acc[4] = {{0,0,0,0},{0,0,0,0},{0,0,0,0},{0,0,0,0}};
  float deP = 0.f;
  const float* __restrict__ Hp = H + (e0 + eL);   // column e0+eL; + n*E_COLS per row
  const int k0 = s * 125, k1 = k0 + 125;
  for (int kk = k0; kk < k1; ++kk) {
    const int nb = kk * 32 + q * 8;               // B-frag: B[k=8q+j][col=eL] = H[nb+j][e0+eL]
    float v[8];
    #pragma unroll
    for (int j = 0; j < 8; ++j) v[j] = Hp[(long)(nb + j) * E_COLS];
    #pragma unroll
    for (int j = 0; j < 8; ++j) deP += v[j];
    union { s16x8 v8; unsigned short u[8]; } bf;
    #pragma unroll
    for (int j = 0; j < 8; ++j) bf.u[j] = f2bf(v[j]);
    #pragma unroll
    for (int ct = 0; ct < 4; ++ct) {              // A-frag: A[m=c=16ct+eL][k=nb+j], contiguous bf16
      s16x8 af = *(const s16x8*)&xwT[(long)(ct * 16 + eL) * N_ROWS + nb];
      acc[ct] = __builtin_amdgcn_mfma_f32_16x16x32_bf16(af, bf.v8, acc[ct], 0, 0, 0);
    }
  }
  // D layout: row(c) = 4q+r, col(e) = eL  [measured m89]
  #pragma unroll
  for (int ct = 0; ct < 4; ++ct)
    #pragma unroll
    for (int r = 0; r < 4; ++r) {
      int c = ct * 16 + q * 4 + r;
      atomicAdd(&eacc[(long)c * E_PAD + e0 + eL], acc[ct][r]);
    }
  deP += __shfl_xor(deP, 16, 64);
  deP += __shfl_xor(deP, 32, 64);
  if (l < 16) atomicAdd(&de[e0 + l], deP);
}

// ---------------- kernel 3: edgeT[c][e] = bf16(eacc[c][e]/de[e]); zero pad ----------
__global__ __launch_bounds__(256) void k3_edgefin(const float* __restrict__ eacc,
                                                  const float* __restrict__ de,
                                                  unsigned short* __restrict__ eT) {
  const int e = blockIdx.x * 256 + threadIdx.x;
  const int c = blockIdx.y;
  if (e >= E_PAD) return;
  float v = 0.f;
  if (e < E_COLS) v = eacc[(long)c * E_PAD + e] / de[e];
  eT[(long)c * E_PAD + e] = f2bf(v);
}

// ---------------- kernel 4: out[n][c] += sum_e H[n][e]*edgeT[c][e]; dn[n] += rowsum --
// grid: 1250 m-tiles x 4 K-chunks = 5000 blocks of 1 wave. 313 ksteps (last masked).
__global__ __launch_bounds__(64) void k4_node(const float* __restrict__ H,
                                              const unsigned short* __restrict__ eT,
                                              float* __restrict__ outacc,
                                              float* __restrict__ dn) {
  const int b  = blockIdx.x;
  const int mt = b % 1250, s = b / 1250;
  const int n0 = mt * 16;
  const int l  = threadIdx.x;
  const int q  = l >> 4, nL = l & 15;
  f32x4 acc[4] = {{0,0,0,0},{0,0,0,0},{0,0,0,0},{0,0,0,0}};
  float dnP = 0.f;
  const float* __restrict__ Hrow = H + (long)(n0 + nL) * E_COLS;
  const int k0 = s * 78;
  const int k1 = (s == 3) ? 313 : (k0 + 78);
  const f32x4 z4 = {0, 0, 0, 0};
  for (int kk = k0; kk < k1; ++kk) {
    const int ec = kk * 32 + q * 8;               // A-frag: A[m=n=n0+nL][k=ec+j], 8 consec f32
    f32x4 v0 = (ec     < E_COLS) ? *(const f32x4*)(Hrow + ec)     : z4;  // mask only fires kk=312
    f32x4 v1 = (ec + 4 < E_COLS) ? *(const f32x4*)(Hrow + ec + 4) : z4;
    dnP += v0[0] + v0[1] + v0[2] + v0[3] + v1[0] + v1[1] + v1[2] + v1[3];
    union { s16x8 v8; unsigned short u[8]; } af;
    #pragma unroll
    for (int j = 0; j < 4; ++j) { af.u[j] = f2bf(v0[j]); af.u[4 + j] = f2bf(v1[j]); }
    #pragma unroll
    for (int ct = 0; ct < 4; ++ct) {              // B-frag: B[k=e][col=c=16ct+nL] = eT[c][e], contiguous
      s16x8 bf = *(const s16x8*)&eT[(long)(ct * 16 + nL) * E_PAD + ec];
      acc[ct] = __builtin_amdgcn_mfma_f32_16x16x32_bf16(af.v8, bf, acc[ct], 0, 0, 0);
    }
  }
  // D layout: row(n) = 4q+r, col(c) = nL
  #pragma unroll
  for (int ct = 0; ct < 4; ++ct)
    #pragma unroll
    for (int r = 0; r < 4; ++r)
      atomicAdd(&outacc[(long)(n0 + q * 4 + r) * OUT_CH + ct * 16 + nL], acc[ct][r]);
  dnP += __shfl_xor(dnP, 16, 64);
  dnP += __shfl_xor(dnP, 32, 64);
  if (l < 16) atomicAdd(&dn[n0 + l], dnP);
}

// ---------------- kernel 5: out /= dn ----------------
__global__ __launch_bounds__(256) void k5_nodefin(float* __restrict__ out,
                                                  const float* __restrict__ dn) {
  const int idx = blockIdx.x * 256 + threadIdx.x;  // exactly 20000*64 = 5000*256
  out[idx] = out[idx] / dn[idx >> 6];
}

extern "C" void kernel_launch(void* const* d_in, const int* in_sizes, int n_in,
                              void* d_out, int out_size, void* d_ws, size_t ws_size,
                              hipStream_t stream) {
  const float* x     = (const float*)d_in[0];
  const float* H     = (const float*)d_in[1];
  const float* theta = (const float*)d_in[2];
  float* out = (float*)d_out;
  char* ws = (char*)d_ws;

  // workspace layout (all offsets 256B-aligned), total ~6.53 MB
  const size_t OFF_XWT  = 0;                         // bf16 [64][20000]  = 2,560,000
  const size_t OFF_EACC = 2560000;                   // f32  [64][10016]  = 2,564,096
  const size_t OFF_DE   = OFF_EACC + 2564096;        // f32  [10016]      =    40,064 -> pad 40,192
  const size_t OFF_DN   = OFF_DE + 40192;            // f32  [20000]      =    80,000 -> pad 80,128
  const size_t OFF_ET   = OFF_DN + 80128;            // bf16 [64][10016]  = 1,282,048

  unsigned short* xwT = (unsigned short*)(ws + OFF_XWT);
  float*          eacc = (float*)(ws + OFF_EACC);
  float*          de   = (float*)(ws + OFF_DE);
  float*          dn   = (float*)(ws + OFF_DN);
  unsigned short* eT   = (unsigned short*)(ws + OFF_ET);

  // zero accumulators (ws/d_out are poisoned 0xAA before every launch)
  hipMemsetAsync(eacc, 0, 2564096, stream);
  hipMemsetAsync(de,   0, 40064,   stream);
  hipMemsetAsync(dn,   0, 80000,   stream);
  hipMemsetAsync(out,  0, (size_t)out_size * sizeof(float), stream);

  k1_xwt<<<313, 256, 0, stream>>>(x, theta, xwT);
  k2_edge<<<3125, 64, 0, stream>>>(H, xwT, eacc, de);
  k3_edgefin<<<dim3(40, 64), 256, 0, stream>>>(eacc, de, eT);
  k4_node<<<5000, 64, 0, stream>>>(H, eT, out, dn);
  k5_nodefin<<<5000, 256, 0, stream>>>(out, dn);
}

// Round 2
// 1409.914 us; speedup vs baseline: 1.0822x; 1.0822x over previous
//
#include <hip/hip_runtime.h>

// DAHHConv: out = Dn^-1 H De^-1 H^T (x @ theta)
// N=20000, E=10000, in=128, out=64. H DENSE f32 [N,E] = 800MB, streamed twice.
// R2 change: k2 now reads H ROW-MAJOR in 512B bursts and transposes via LDS
// (R1 read columns in 64B segments -> ~2x fetch + DRAM page thrash; suspected ~900us).

#define N_ROWS 20000
#define E_COLS 10000
#define ETILE  128
#define E_PAD2 10112   // 79*128, zero-padded tail
#define OUT_CH 64

typedef __attribute__((ext_vector_type(4))) float f32x4;
typedef __attribute__((ext_vector_type(8))) short s16x8;

__device__ __forceinline__ unsigned short f2bf(float f) {
  unsigned int u = __float_as_uint(f);
  u += 0x7FFFu + ((u >> 16) & 1u);
  return (unsigned short)(u >> 16);
}

// ---------------- kernel 1: xwT[c][n] = (x @ theta)^T, stored bf16 ----------------
__global__ __launch_bounds__(256) void k1_xwt(const float* __restrict__ x,
                                              const float* __restrict__ theta,
                                              unsigned short* __restrict__ xwT) {
  __shared__ float xt[64][129];
  const int n0 = blockIdx.x * 64;
  const int t  = threadIdx.x;
  #pragma unroll
  for (int i = 0; i < 8; ++i) {
    int f  = t + 256 * i;
    int r  = f >> 5;
    int c4 = (f & 31) * 4;
    float4 v = make_float4(0.f, 0.f, 0.f, 0.f);
    if (n0 + r < N_ROWS) v = *(const float4*)&x[(long)(n0 + r) * 128 + c4];
    xt[r][c4] = v.x; xt[r][c4 + 1] = v.y; xt[r][c4 + 2] = v.z; xt[r][c4 + 3] = v.w;
  }
  __syncthreads();
  const int nl = t & 63;
  const int cg = t >> 6;
  const int n  = n0 + nl;
  float acc[16];
  #pragma unroll
  for (int i = 0; i < 16; ++i) acc[i] = 0.f;
  #pragma unroll 4
  for (int k = 0; k < 128; ++k) {
    float xv = xt[nl][k];
    const float* th = theta + k * 64 + cg * 16;
    #pragma unroll
    for (int i = 0; i < 16; ++i) acc[i] += xv * th[i];
  }
  if (n < N_ROWS) {
    #pragma unroll
    for (int i = 0; i < 16; ++i)
      xwT[(long)(cg * 16 + i) * N_ROWS + n] = f2bf(acc[i]);
  }
}

// ---------------- kernel 2: eacc[c][e] += sum_n xwT[c][n]*H[n][e]; de[e] += colsum ----
// grid: 79 e-tiles x 25 K-chunks = 1975 blocks x 256 threads (4 waves).
// Per iter: stage H[32n][128e] f32 row-major (512B bursts) -> LDS, transpose-read
// B-frags, MFMA vs L2-resident xwT A-frags. Next tile prefetched into regs.
__global__ __launch_bounds__(256) void k2_edge(const float* __restrict__ H,
                                               const unsigned short* __restrict__ xwT,
                                               float* __restrict__ eacc,
                                               float* __restrict__ de) {
  __shared__ float tile[32][ETILE + 4];   // +4: rows 16B-aligned for ds_write_b128
  const int b  = blockIdx.x;
  const int et = b % 79, s = b / 79;
  const int e0 = et * ETILE;
  const int t  = threadIdx.x;
  const int w  = t >> 6;                  // wave id 0..3 -> cols [32w, 32w+32)
  const int l  = t & 63;
  const int q  = l >> 4, eL = l & 15;

  const int sr = t >> 5;                  // staging row 0..7 (+8 per round)
  const int sc = (t & 31) * 4;            // staging col
  const int eg = e0 + sc;                 // kk-invariant guard
  const bool egv = (eg < E_COLS);
  const f32x4 z4 = {0, 0, 0, 0};

  f32x4 acc[2][4];
  #pragma unroll
  for (int sub = 0; sub < 2; ++sub)
    #pragma unroll
    for (int ct = 0; ct < 4; ++ct) acc[sub][ct] = z4;
  float deP[2] = {0.f, 0.f};

  const int c0 = 25 * s, c1 = c0 + 25;    // 625 = 25*25 n-chunks of 32 rows

  f32x4 pv[4];
  #pragma unroll
  for (int i = 0; i < 4; ++i)
    pv[i] = egv ? *(const f32x4*)&H[(long)(c0 * 32 + sr + 8 * i) * E_COLS + eg] : z4;

  for (int kk = c0; kk < c1; ++kk) {
    const int nb = kk * 32;
    // write staged tile
    #pragma unroll
    for (int i = 0; i < 4; ++i)
      *(f32x4*)&tile[sr + 8 * i][sc] = pv[i];
    __syncthreads();
    // prefetch next tile (overlaps consume below)
    if (kk + 1 < c1) {
      #pragma unroll
      for (int i = 0; i < 4; ++i)
        pv[i] = egv ? *(const f32x4*)&H[(long)(nb + 32 + sr + 8 * i) * E_COLS + eg] : z4;
    }
    // A-frags: A[m=c][k=n], 8 consecutive bf16 from xwT (L2-resident)
    s16x8 af[4];
    #pragma unroll
    for (int ct = 0; ct < 4; ++ct)
      af[ct] = *(const s16x8*)&xwT[(long)(ct * 16 + eL) * N_ROWS + nb + 8 * q];
    // B-frags from LDS transpose; fused de colsum
    #pragma unroll
    for (int sub = 0; sub < 2; ++sub) {
      const int ec = 32 * w + 16 * sub + eL;
      union { s16x8 v8; unsigned short u[8]; } bf;
      float ds = 0.f;
      #pragma unroll
      for (int j = 0; j < 8; ++j) {
        float v = tile[8 * q + j][ec];
        ds += v;
        bf.u[j] = f2bf(v);
      }
      deP[sub] += ds;
      #pragma unroll
      for (int ct = 0; ct < 4; ++ct)
        acc[sub][ct] = __builtin_amdgcn_mfma_f32_16x16x32_bf16(af[ct], bf.v8, acc[sub][ct], 0, 0, 0);
    }
    __syncthreads();   // all LDS reads done before next write
  }
  // D layout: row(c) = 4q+r, col(e) = eL
  #pragma unroll
  for (int sub = 0; sub < 2; ++sub)
    #pragma unroll
    for (int ct = 0; ct < 4; ++ct)
      #pragma unroll
      for (int r = 0; r < 4; ++r) {
        int c = ct * 16 + q * 4 + r;
        int e = e0 + 32 * w + 16 * sub + eL;
        atomicAdd(&eacc[(long)c * E_PAD2 + e], acc[sub][ct][r]);
      }
  #pragma unroll
  for (int sub = 0; sub < 2; ++sub) {
    float d = deP[sub];
    d += __shfl_xor(d, 16, 64);
    d += __shfl_xor(d, 32, 64);
    if (l < 16) atomicAdd(&de[e0 + 32 * w + 16 * sub + l], d);
  }
}

// ---------------- kernel 3: edgeT[c][e] = bf16(eacc[c][e]/de[e]); zero pad ----------
__global__ __launch_bounds__(256) void k3_edgefin(const float* __restrict__ eacc,
                                                  const float* __restrict__ de,
                                                  unsigned short* __restrict__ eT) {
  const int e = blockIdx.x * 256 + threadIdx.x;
  const int c = blockIdx.y;
  if (e >= E_PAD2) return;
  float v = 0.f;
  if (e < E_COLS) v = eacc[(long)c * E_PAD2 + e] / de[e];
  eT[(long)c * E_PAD2 + e] = f2bf(v);
}

// ---------------- kernel 4: out[n][c] += sum_e H[n][e]*edgeT[c][e]; dn[n] += rowsum --
// grid: 1250 m-tiles x 4 K-chunks = 5000 blocks of 1 wave. 316 ksteps, 79/chunk.
__global__ __launch_bounds__(64) void k4_node(const float* __restrict__ H,
                                              const unsigned short* __restrict__ eT,
                                              float* __restrict__ outacc,
                                              float* __restrict__ dn) {
  const int b  = blockIdx.x;
  const int mt = b % 1250, s = b / 1250;
  const int n0 = mt * 16;
  const int l  = threadIdx.x;
  const int q  = l >> 4, nL = l & 15;
  f32x4 acc[4] = {{0,0,0,0},{0,0,0,0},{0,0,0,0},{0,0,0,0}};
  float dnP = 0.f;
  const float* __restrict__ Hrow = H + (long)(n0 + nL) * E_COLS;
  const int k0 = s * 79, k1 = k0 + 79;
  const f32x4 z4 = {0, 0, 0, 0};
  for (int kk = k0; kk < k1; ++kk) {
    const int ec = kk * 32 + q * 8;
    f32x4 v0 = (ec     < E_COLS) ? *(const f32x4*)(Hrow + ec)     : z4;
    f32x4 v1 = (ec + 4 < E_COLS) ? *(const f32x4*)(Hrow + ec + 4) : z4;
    dnP += v0[0] + v0[1] + v0[2] + v0[3] + v1[0] + v1[1] + v1[2] + v1[3];
    union { s16x8 v8; unsigned short u[8]; } af;
    #pragma unroll
    for (int j = 0; j < 4; ++j) { af.u[j] = f2bf(v0[j]); af.u[4 + j] = f2bf(v1[j]); }
    #pragma unroll
    for (int ct = 0; ct < 4; ++ct) {
      s16x8 bf = *(const s16x8*)&eT[(long)(ct * 16 + nL) * E_PAD2 + ec];
      acc[ct] = __builtin_amdgcn_mfma_f32_16x16x32_bf16(af.v8, bf, acc[ct], 0, 0, 0);
    }
  }
  #pragma unroll
  for (int ct = 0; ct < 4; ++ct)
    #pragma unroll
    for (int r = 0; r < 4; ++r)
      atomicAdd(&outacc[(long)(n0 + q * 4 + r) * OUT_CH + ct * 16 + nL], acc[ct][r]);
  dnP += __shfl_xor(dnP, 16, 64);
  dnP += __shfl_xor(dnP, 32, 64);
  if (l < 16) atomicAdd(&dn[n0 + l], dnP);
}

// ---------------- kernel 5: out /= dn ----------------
__global__ __launch_bounds__(256) void k5_nodefin(float* __restrict__ out,
                                                  const float* __restrict__ dn) {
  const int idx = blockIdx.x * 256 + threadIdx.x;
  out[idx] = out[idx] / dn[idx >> 6];
}

extern "C" void kernel_launch(void* const* d_in, const int* in_sizes, int n_in,
                              void* d_out, int out_size, void* d_ws, size_t ws_size,
                              hipStream_t stream) {
  const float* x     = (const float*)d_in[0];
  const float* H     = (const float*)d_in[1];
  const float* theta = (const float*)d_in[2];
  float* out = (float*)d_out;
  char* ws = (char*)d_ws;

  // workspace layout (256B-aligned offsets), total ~6.56 MB
  const size_t OFF_XWT  = 0;                    // bf16 [64][20000] = 2,560,000
  const size_t OFF_EACC = 2560000;              // f32  [64][10112] = 2,588,672
  const size_t OFF_DE   = OFF_EACC + 2588672;   // f32  [10112]     = 40,448
  const size_t OFF_DN   = OFF_DE + 40448;       // f32  [20000]     = 80,000 -> pad 80,128
  const size_t OFF_ET   = OFF_DN + 80128;       // bf16 [64][10112] = 1,294,336

  unsigned short* xwT  = (unsigned short*)(ws + OFF_XWT);
  float*          eacc = (float*)(ws + OFF_EACC);
  float*          de   = (float*)(ws + OFF_DE);
  float*          dn   = (float*)(ws + OFF_DN);
  unsigned short* eT   = (unsigned short*)(ws + OFF_ET);

  hipMemsetAsync(eacc, 0, 2588672, stream);
  hipMemsetAsync(de,   0, 40448,   stream);
  hipMemsetAsync(dn,   0, 80000,   stream);
  hipMemsetAsync(out,  0, (size_t)out_size * sizeof(float), stream);

  k1_xwt<<<313, 256, 0, stream>>>(x, theta, xwT);
  k2_edge<<<1975, 256, 0, stream>>>(H, xwT, eacc, de);
  k3_edgefin<<<dim3(40, 64), 256, 0, stream>>>(eacc, de, eT);
  k4_node<<<5000, 64, 0, stream>>>(H, eT, out, dn);
  k5_nodefin<<<5000, 256, 0, stream>>>(out, dn);
}